// Round 12
// baseline (281.192 us; speedup 1.0000x reference)
//
#include <hip/hip_runtime.h>

#define PI_F 3.14159265358979323846f

// ws layout (bytes):
//   24576    : maxz — u32 maxraw[3*32] | maxdiff[3] @96 | done @99
//              (all zeroed by bin block 0)
//   32768    : packed hist u8: 3 planes × 32 hists × 262144 bins = 24 MB
//   25198592 : triples u32: 32 images × 524288 points = 64 MB (all 3 planes)
#define MAXZ_OFF_B   24576
#define HIST_OFF_B   32768
#define BINS_OFF_B   25198592

// Correctly-rounded a/20000 via Markstein refinement (bit-exact RN).
__device__ inline float div20000(float a) {
    const float r = 1.0f / 20000.0f;
    float q0 = a * r;
    float e = fmaf(-20000.0f, q0, a);
    return fmaf(e, r, q0);
}

__device__ inline int bin1(float v) {
    float f = rintf(div20000(v + 10000.0f) * 512.0f);
    return (int)fminf(fmaxf(f, 0.0f), 511.0f);
}

// Pass 1: 4096 blocks = (xcd[0:2], i4[3:9], hh[10:11]), 4 rows/block,
// XCD-pinned (wg&7 == h&7). Trig computed in-kernel (bit-identical bins).
// Block 0 zeroes maxz + out (ordered before consumers by kernel boundary).
__global__ __launch_bounds__(256) void bin_kernel(
    const float* __restrict__ pred, const float* __restrict__ gt,
    unsigned* __restrict__ bins, unsigned* __restrict__ maxz,
    float* __restrict__ out) {
    __shared__ float sct[4], sst[4];
    const int tid = threadIdx.x, wg = blockIdx.x;
    const int xcd = wg & 7, i4 = (wg >> 3) & 127, hh = wg >> 10;
    const int h = (hh << 3) | xcd;
    if (wg == 0) {
        if (tid < 128) maxz[tid] = 0u;
        if (tid == 128) out[0] = 0.0f;
    }
    if (tid < 4) {
        float fi = (float)(i4 * 4 + tid);
        float theta = -PI_F * (fi / 511.0f - 0.5f);
        sct[tid] = cosf(theta);
        sst[tid] = sinf(theta);
    }
    float cp[4], sp[4];
    #pragma unroll
    for (int k = 0; k < 4; ++k) {
        float fj = (float)(tid * 4 + k);
        float phi = PI_F * ((2.0f * fj) / 1023.0f - 1.0f);
        cp[k] = cosf(phi);
        sp[k] = sinf(phi);
    }
    __syncthreads();
    const float* img = ((h >> 4) ? gt : pred) + ((h & 15) << 19);
    #pragma unroll
    for (int r = 0; r < 4; ++r) {
        const int i = i4 * 4 + r;
        const float4 d4 = *(const float4*)(img + (i << 10) + (tid << 2));
        const float ct = sct[r], st = sst[r];
        uint4 o;
        #pragma unroll
        for (int k = 0; k < 4; ++k) {
            float d = (&d4.x)[k];
            float aA = cp[k] * ct;              // identical op order to r3/r5
            float aB = sp[k] * ct;
            float A = (d * aA) * 1000.0f;
            float B = (d * aB) * 1000.0f;
            float C = (d * (-st)) * 1000.0f;
            int iA = bin1(A), iB = bin1(B), iC = bin1(C);
            (&o.x)[k] = ((unsigned)iC << 18) | ((unsigned)iB << 9) | (unsigned)iA;
        }
        *(uint4*)(bins + ((unsigned)h << 19) + (i << 10) + (tid << 2)) = o;
    }
}

// Pass 2: WG = (plane, h, 64-row band); 1024 threads, 2 blocks/CU = 32
// waves/CU; uint4 loads, 1-deep prefetch; analytic conservative row interval
// (superset of exact — extra rows hold zero in-band points).
__global__ __launch_bounds__(1024, 8) void scan_kernel(
    const unsigned* __restrict__ bins, unsigned* __restrict__ hp,
    unsigned* __restrict__ maxraw) {
    __shared__ unsigned lh[16384];              // 64 rows × 512 bins, u16×2
    __shared__ unsigned s4[16];
    const int tid = threadIdx.x, wg = blockIdx.x;
    const int xcd = wg & 7, hhi = (wg >> 3) & 3;
    const int X = wg >> 5;                      // 0..23
    const int pair = X / 6, idx6 = X % 6;
    const int plane = idx6 >> 1;
    const int band = (idx6 & 1) ? (4 + pair) : (3 - pair);
    const int h = (hhi << 3) | xcd;

    #pragma unroll
    for (int k = 0; k < 4; ++k)
        *(uint4*)&lh[(k << 12) + (tid << 2)] = make_uint4(0, 0, 0, 0);
    __syncthreads();

    int rlo, rhi;
    if (plane == 0) {
        float g = fmaxf(193.0f - 64.0f * band, 64.0f * band - 256.0f);
        float cmin = (g - 4.0f) * (1.0f / 256.0f);
        if (cmin <= 0.0f) { rlo = 0; rhi = 512; }
        else {
            float L = 511.0f * acosf(fminf(cmin, 1.0f)) / PI_F;
            rlo = max(0, (int)floorf(255.5f - L) - 3);
            rhi = min(512, (int)ceilf(255.5f + L) + 4);
        }
    } else if (band == 3) { rlo = 0; rhi = 260; }
    else if (band == 4) { rlo = 0; rhi = 512; }
    else if (band < 3) {
        float smin = (189.0f - 64.0f * band) * (1.0f / 256.0f);
        rlo = 0;
        rhi = min(512, (int)ceilf(511.0f * (0.5f - asinf(smin) / PI_F)) + 4);
    } else {
        float smin = (64.0f * band - 260.0f) * (1.0f / 256.0f);
        rhi = 512;
        rlo = max(0, (int)floorf(511.0f * (0.5f + asinf(smin) / PI_F)) - 4);
    }

    int s1, m1, m2, bsh;
    if (plane == 0)      { s1 = 0; m1 = 0x7FFF; m2 = 0;   bsh = 15; }
    else if (plane == 1) { s1 = 9; m1 = 0x7E00; m2 = 511; bsh = 24; }
    else                 { s1 = 9; m1 = 0x7FFF; m2 = 0;   bsh = 24; }
    const unsigned bandu = (unsigned)band;
    const unsigned* src = bins + ((unsigned)h << 19);

    auto process = [&](uint4 v) {
        #pragma unroll
        for (int k = 0; k < 4; ++k) {
            unsigned b = (&v.x)[k];
            if (((b >> bsh) & 7u) == bandu) {
                unsigned id = ((b >> s1) & m1) | (b & m2);
                atomicAdd(&lh[id >> 1], 1u << ((id & 1u) << 4));
            }
        }
    };

    const int t4 = (tid & 255) << 2;
    const int rof = tid >> 8;
    int r = rlo + rof;
    uint4 cur = make_uint4(0u, 0u, 0u, 0u);
    if (r < rhi) cur = *(const uint4*)&src[(r << 10) + t4];
    for (int rbase = rlo; rbase < rhi; rbase += 4) {
        int rn = rbase + 4 + rof;
        uint4 nxt = make_uint4(0u, 0u, 0u, 0u);
        if (rn < rhi) nxt = *(const uint4*)&src[(rn << 10) + t4];
        if (rbase + rof < rhi) process(cur);
        cur = nxt;
    }
    __syncthreads();

    unsigned m = 0;
    unsigned* gout = hp + ((plane * 32 + h) << 16) + (band << 13);
    #pragma unroll
    for (int k = 0; k < 8; ++k) {
        int w = (k << 10) + tid;
        unsigned v0 = lh[2 * w], v1 = lh[2 * w + 1];
        unsigned c0 = v0 & 65535u, c1 = v0 >> 16;
        unsigned c2 = v1 & 65535u, c3 = v1 >> 16;
        m = max(max(m, max(c0, c1)), max(c2, c3));
        gout[w] = min(c0, 255u) | (min(c1, 255u) << 8) |
                  (min(c2, 255u) << 16) | (min(c3, 255u) << 24);
    }
    #pragma unroll
    for (int o = 32; o; o >>= 1) m = max(m, (unsigned)__shfl_down((int)m, o));
    if ((tid & 63) == 0) s4[tid >> 6] = m;
    __syncthreads();
    if (tid == 0) {
        #pragma unroll
        for (int k = 1; k < 16; ++k) m = max(m, s4[k]);
        atomicMax(&maxraw[plane * 32 + h], m);
    }
}

// Fused maxdiff+loss: 768 blocks × 256 thr, __launch_bounds__(256,3) =>
// 3 blocks/CU × 256 CU = 768 — whole grid co-resident, spin cannot deadlock.
// r11 lesson: poll with device-scope atomic LOAD (coherent global_load, no
// RMW serialization) — RMW polling from 768 leaders serialized the fabric
// and stretched the barrier by ~50 µs.
__global__ __launch_bounds__(256, 3) void tail_kernel(
    const unsigned* __restrict__ hp, const unsigned* __restrict__ maxraw,
    unsigned* maxdiff, unsigned* done, float* __restrict__ out) {
    __shared__ float sred[4];
    __shared__ float sc;
    int blk = blockIdx.x;
    int b = blk & 15, chunk = (blk >> 4) & 15, plane = blk >> 8;
    const unsigned* P = hp + ((plane * 32 + b) << 16) + (chunk << 12);
    const unsigned* G = P + (16 << 16);
    float nP = fminf((float)maxraw[plane * 32 + b], 100.0f);
    float nG = fminf((float)maxraw[plane * 32 + 16 + b], 100.0f);

    uint4 wp[4], wg[4];
    #pragma unroll
    for (int k = 0; k < 4; ++k) {
        wp[k] = *(const uint4*)&P[(k << 10) + (threadIdx.x << 2)];
        wg[k] = *(const uint4*)&G[(k << 10) + (threadIdx.x << 2)];
    }

    // phase 1: chunk max |pn-gn|
    float m = 0.0f;
    #pragma unroll
    for (int k = 0; k < 4; ++k) {
        #pragma unroll
        for (int w = 0; w < 4; ++w) {
            unsigned up = (&wp[k].x)[w], ug = (&wg[k].x)[w];
            #pragma unroll
            for (int s = 0; s < 32; s += 8) {
                float pn = fminf((float)((up >> s) & 255u), 100.0f) / nP;
                float gn = fminf((float)((ug >> s) & 255u), 100.0f) / nG;
                m = fmaxf(m, fabsf(pn - gn));
            }
        }
    }
    #pragma unroll
    for (int o = 32; o; o >>= 1) m = fmaxf(m, __shfl_down(m, o));
    if ((threadIdx.x & 63) == 0) sred[threadIdx.x >> 6] = m;
    __syncthreads();
    if (threadIdx.x == 0) {
        m = fmaxf(fmaxf(sred[0], sred[1]), fmaxf(sred[2], sred[3]));
        atomicMax(&maxdiff[plane], __float_as_uint(m));
        __threadfence();                         // release maxdiff
        atomicAdd(done, 1u);                     // single arrival RMW
        while (__hip_atomic_load(done, __ATOMIC_RELAXED,
                                 __HIP_MEMORY_SCOPE_AGENT) < 768u)
            __builtin_amdgcn_s_sleep(32);        // load-poll: no RMW traffic
        __threadfence();                         // acquire all maxdiff
        sc = 0.2f * __uint_as_float(__hip_atomic_load(
                 &maxdiff[plane], __ATOMIC_RELAXED, __HIP_MEMORY_SCOPE_AGENT));
    }
    __syncthreads();
    const float c = sc;

    // phase 2: berHu sum from registers
    float acc = 0.0f;
    #pragma unroll
    for (int k = 0; k < 4; ++k) {
        #pragma unroll
        for (int w = 0; w < 4; ++w) {
            unsigned up = (&wp[k].x)[w], ug = (&wg[k].x)[w];
            #pragma unroll
            for (int s = 0; s < 32; s += 8) {
                float pn = fminf((float)((up >> s) & 255u), 100.0f) / nP;
                float gn = fminf((float)((ug >> s) & 255u), 100.0f) / nG;
                float d = fabsf(pn - gn);
                acc += (d <= c) ? d : (d * d + c * c) / (2.0f * c);
            }
        }
    }
    #pragma unroll
    for (int o = 32; o; o >>= 1) acc += __shfl_down(acc, o);
    __syncthreads();                             // reuse sred
    if ((threadIdx.x & 63) == 0) sred[threadIdx.x >> 6] = acc;
    __syncthreads();
    if (threadIdx.x == 0) {
        acc = (sred[0] + sred[1]) + (sred[2] + sred[3]);
        atomicAdd(out, acc / 4194304.0f);        // exact 2^-22 scale
    }
}

extern "C" void kernel_launch(void* const* d_in, const int* in_sizes, int n_in,
                              void* d_out, int out_size, void* d_ws, size_t ws_size,
                              hipStream_t stream) {
    const float* pred = (const float*)d_in[0];
    const float* gt   = (const float*)d_in[1];
    float* out        = (float*)d_out;
    char* ws          = (char*)d_ws;

    unsigned* maxz    = (unsigned*)(ws + MAXZ_OFF_B);
    unsigned* maxraw  = maxz;                    // [0..95]
    unsigned* maxdiff = maxz + 96;               // [96..98]
    unsigned* done    = maxz + 99;               // [99]
    unsigned* hp      = (unsigned*)(ws + HIST_OFF_B);
    unsigned* bins    = (unsigned*)(ws + BINS_OFF_B);

    bin_kernel<<<4096, 256, 0, stream>>>(pred, gt, bins, maxz, out);
    scan_kernel<<<768, 1024, 0, stream>>>(bins, hp, maxraw);
    tail_kernel<<<768, 256, 0, stream>>>(hp, maxraw, maxdiff, done, out);
}

// Round 13
// 267.589 us; speedup vs baseline: 1.0508x; 1.0508x over previous
//
#include <hip/hip_runtime.h>

#define PI_F 3.14159265358979323846f

// ws layout (bytes):
//   24576    : maxz — u32 maxraw[3*32] | maxdiff[3] @96 | done @99
//              (all zeroed by bin block 0)
//   32768    : packed hist u8: 3 planes × 32 hists × 262144 bins = 24 MB
//   25198592 : triples u32: 32 images × 524288 points = 64 MB (all 3 planes)
#define MAXZ_OFF_B   24576
#define HIST_OFF_B   32768
#define BINS_OFF_B   25198592

// Correctly-rounded a/20000 via Markstein refinement (bit-exact RN).
__device__ inline float div20000(float a) {
    const float r = 1.0f / 20000.0f;
    float q0 = a * r;
    float e = fmaf(-20000.0f, q0, a);
    return fmaf(e, r, q0);
}

__device__ inline int bin1(float v) {
    float f = rintf(div20000(v + 10000.0f) * 512.0f);
    return (int)fminf(fmaxf(f, 0.0f), 511.0f);
}

// Pass 1: 4096 blocks = (xcd[0:2], i4[3:9], hh[10:11]), 4 rows/block,
// XCD-pinned (wg&7 == h&7). Trig computed in-kernel (bit-identical bins).
// Block 0 zeroes maxz + out (ordered before consumers by kernel boundary).
__global__ __launch_bounds__(256) void bin_kernel(
    const float* __restrict__ pred, const float* __restrict__ gt,
    unsigned* __restrict__ bins, unsigned* __restrict__ maxz,
    float* __restrict__ out) {
    __shared__ float sct[4], sst[4];
    const int tid = threadIdx.x, wg = blockIdx.x;
    const int xcd = wg & 7, i4 = (wg >> 3) & 127, hh = wg >> 10;
    const int h = (hh << 3) | xcd;
    if (wg == 0) {
        if (tid < 128) maxz[tid] = 0u;
        if (tid == 128) out[0] = 0.0f;
    }
    if (tid < 4) {
        float fi = (float)(i4 * 4 + tid);
        float theta = -PI_F * (fi / 511.0f - 0.5f);
        sct[tid] = cosf(theta);
        sst[tid] = sinf(theta);
    }
    float cp[4], sp[4];
    #pragma unroll
    for (int k = 0; k < 4; ++k) {
        float fj = (float)(tid * 4 + k);
        float phi = PI_F * ((2.0f * fj) / 1023.0f - 1.0f);
        cp[k] = cosf(phi);
        sp[k] = sinf(phi);
    }
    __syncthreads();
    const float* img = ((h >> 4) ? gt : pred) + ((h & 15) << 19);
    #pragma unroll
    for (int r = 0; r < 4; ++r) {
        const int i = i4 * 4 + r;
        const float4 d4 = *(const float4*)(img + (i << 10) + (tid << 2));
        const float ct = sct[r], st = sst[r];
        uint4 o;
        #pragma unroll
        for (int k = 0; k < 4; ++k) {
            float d = (&d4.x)[k];
            float aA = cp[k] * ct;              // identical op order to r3/r5
            float aB = sp[k] * ct;
            float A = (d * aA) * 1000.0f;
            float B = (d * aB) * 1000.0f;
            float C = (d * (-st)) * 1000.0f;
            int iA = bin1(A), iB = bin1(B), iC = bin1(C);
            (&o.x)[k] = ((unsigned)iC << 18) | ((unsigned)iB << 9) | (unsigned)iA;
        }
        *(uint4*)(bins + ((unsigned)h << 19) + (i << 10) + (tid << 2)) = o;
    }
}

// Pass 2: WG = (plane, h, 64-row band); 1024 threads, 2 blocks/CU = 32
// waves/CU; uint4 loads, 1-deep prefetch; analytic conservative row interval
// (superset of exact — extra rows hold zero in-band points).
__global__ __launch_bounds__(1024, 8) void scan_kernel(
    const unsigned* __restrict__ bins, unsigned* __restrict__ hp,
    unsigned* __restrict__ maxraw) {
    __shared__ unsigned lh[16384];              // 64 rows × 512 bins, u16×2
    __shared__ unsigned s4[16];
    const int tid = threadIdx.x, wg = blockIdx.x;
    const int xcd = wg & 7, hhi = (wg >> 3) & 3;
    const int X = wg >> 5;                      // 0..23
    const int pair = X / 6, idx6 = X % 6;
    const int plane = idx6 >> 1;
    const int band = (idx6 & 1) ? (4 + pair) : (3 - pair);
    const int h = (hhi << 3) | xcd;

    #pragma unroll
    for (int k = 0; k < 4; ++k)
        *(uint4*)&lh[(k << 12) + (tid << 2)] = make_uint4(0, 0, 0, 0);
    __syncthreads();

    int rlo, rhi;
    if (plane == 0) {
        float g = fmaxf(193.0f - 64.0f * band, 64.0f * band - 256.0f);
        float cmin = (g - 4.0f) * (1.0f / 256.0f);
        if (cmin <= 0.0f) { rlo = 0; rhi = 512; }
        else {
            float L = 511.0f * acosf(fminf(cmin, 1.0f)) / PI_F;
            rlo = max(0, (int)floorf(255.5f - L) - 3);
            rhi = min(512, (int)ceilf(255.5f + L) + 4);
        }
    } else if (band == 3) { rlo = 0; rhi = 260; }
    else if (band == 4) { rlo = 0; rhi = 512; }
    else if (band < 3) {
        float smin = (189.0f - 64.0f * band) * (1.0f / 256.0f);
        rlo = 0;
        rhi = min(512, (int)ceilf(511.0f * (0.5f - asinf(smin) / PI_F)) + 4);
    } else {
        float smin = (64.0f * band - 260.0f) * (1.0f / 256.0f);
        rhi = 512;
        rlo = max(0, (int)floorf(511.0f * (0.5f + asinf(smin) / PI_F)) - 4);
    }

    int s1, m1, m2, bsh;
    if (plane == 0)      { s1 = 0; m1 = 0x7FFF; m2 = 0;   bsh = 15; }
    else if (plane == 1) { s1 = 9; m1 = 0x7E00; m2 = 511; bsh = 24; }
    else                 { s1 = 9; m1 = 0x7FFF; m2 = 0;   bsh = 24; }
    const unsigned bandu = (unsigned)band;
    const unsigned* src = bins + ((unsigned)h << 19);

    auto process = [&](uint4 v) {
        #pragma unroll
        for (int k = 0; k < 4; ++k) {
            unsigned b = (&v.x)[k];
            if (((b >> bsh) & 7u) == bandu) {
                unsigned id = ((b >> s1) & m1) | (b & m2);
                atomicAdd(&lh[id >> 1], 1u << ((id & 1u) << 4));
            }
        }
    };

    const int t4 = (tid & 255) << 2;
    const int rof = tid >> 8;
    int r = rlo + rof;
    uint4 cur = make_uint4(0u, 0u, 0u, 0u);
    if (r < rhi) cur = *(const uint4*)&src[(r << 10) + t4];
    for (int rbase = rlo; rbase < rhi; rbase += 4) {
        int rn = rbase + 4 + rof;
        uint4 nxt = make_uint4(0u, 0u, 0u, 0u);
        if (rn < rhi) nxt = *(const uint4*)&src[(rn << 10) + t4];
        if (rbase + rof < rhi) process(cur);
        cur = nxt;
    }
    __syncthreads();

    unsigned m = 0;
    unsigned* gout = hp + ((plane * 32 + h) << 16) + (band << 13);
    #pragma unroll
    for (int k = 0; k < 8; ++k) {
        int w = (k << 10) + tid;
        unsigned v0 = lh[2 * w], v1 = lh[2 * w + 1];
        unsigned c0 = v0 & 65535u, c1 = v0 >> 16;
        unsigned c2 = v1 & 65535u, c3 = v1 >> 16;
        m = max(max(m, max(c0, c1)), max(c2, c3));
        gout[w] = min(c0, 255u) | (min(c1, 255u) << 8) |
                  (min(c2, 255u) << 16) | (min(c3, 255u) << 24);
    }
    #pragma unroll
    for (int o = 32; o; o >>= 1) m = max(m, (unsigned)__shfl_down((int)m, o));
    if ((tid & 63) == 0) s4[tid >> 6] = m;
    __syncthreads();
    if (tid == 0) {
        #pragma unroll
        for (int k = 1; k < 16; ++k) m = max(m, s4[k]);
        atomicMax(&maxraw[plane * 32 + h], m);
    }
}

// Fused maxdiff+loss: 768 blocks × 256 thr, __launch_bounds__(256,3) =>
// 3 blocks/CU × 256 CU = 768 — whole grid co-resident, spin cannot deadlock.
// r11/r12 lesson: NO __threadfence() here — it lowers to buffer_wbl2+buffer_inv
// (full 4 MB L2 writeback+invalidate) in each of 768 leaders, ~55 µs.
// All cross-block communication flows through device-scope atomics (LLC);
// release on arrival / acquire on poll give the needed ordering via
// s_waitcnt only, no cache maintenance.
__global__ __launch_bounds__(256, 3) void tail_kernel(
    const unsigned* __restrict__ hp, const unsigned* __restrict__ maxraw,
    unsigned* maxdiff, unsigned* done, float* __restrict__ out) {
    __shared__ float sred[4];
    __shared__ float sc;
    int blk = blockIdx.x;
    int b = blk & 15, chunk = (blk >> 4) & 15, plane = blk >> 8;
    const unsigned* P = hp + ((plane * 32 + b) << 16) + (chunk << 12);
    const unsigned* G = P + (16 << 16);
    float nP = fminf((float)maxraw[plane * 32 + b], 100.0f);
    float nG = fminf((float)maxraw[plane * 32 + 16 + b], 100.0f);

    uint4 wp[4], wg[4];
    #pragma unroll
    for (int k = 0; k < 4; ++k) {
        wp[k] = *(const uint4*)&P[(k << 10) + (threadIdx.x << 2)];
        wg[k] = *(const uint4*)&G[(k << 10) + (threadIdx.x << 2)];
    }

    // phase 1: chunk max |pn-gn|
    float m = 0.0f;
    #pragma unroll
    for (int k = 0; k < 4; ++k) {
        #pragma unroll
        for (int w = 0; w < 4; ++w) {
            unsigned up = (&wp[k].x)[w], ug = (&wg[k].x)[w];
            #pragma unroll
            for (int s = 0; s < 32; s += 8) {
                float pn = fminf((float)((up >> s) & 255u), 100.0f) / nP;
                float gn = fminf((float)((ug >> s) & 255u), 100.0f) / nG;
                m = fmaxf(m, fabsf(pn - gn));
            }
        }
    }
    #pragma unroll
    for (int o = 32; o; o >>= 1) m = fmaxf(m, __shfl_down(m, o));
    if ((threadIdx.x & 63) == 0) sred[threadIdx.x >> 6] = m;
    __syncthreads();
    if (threadIdx.x == 0) {
        m = fmaxf(fmaxf(sred[0], sred[1]), fmaxf(sred[2], sred[3]));
        atomicMax(&maxdiff[plane], __float_as_uint(m));   // device RMW @ LLC
        // release arrival: s_waitcnt orders the atomicMax; no L2 flush
        __hip_atomic_fetch_add(done, 1u, __ATOMIC_RELEASE,
                               __HIP_MEMORY_SCOPE_AGENT);
        while (__hip_atomic_load(done, __ATOMIC_ACQUIRE,
                                 __HIP_MEMORY_SCOPE_AGENT) < 768u)
            __builtin_amdgcn_s_sleep(8);
        sc = 0.2f * __uint_as_float(__hip_atomic_load(
                 &maxdiff[plane], __ATOMIC_RELAXED, __HIP_MEMORY_SCOPE_AGENT));
    }
    __syncthreads();
    const float c = sc;

    // phase 2: berHu sum from registers
    float acc = 0.0f;
    #pragma unroll
    for (int k = 0; k < 4; ++k) {
        #pragma unroll
        for (int w = 0; w < 4; ++w) {
            unsigned up = (&wp[k].x)[w], ug = (&wg[k].x)[w];
            #pragma unroll
            for (int s = 0; s < 32; s += 8) {
                float pn = fminf((float)((up >> s) & 255u), 100.0f) / nP;
                float gn = fminf((float)((ug >> s) & 255u), 100.0f) / nG;
                float d = fabsf(pn - gn);
                acc += (d <= c) ? d : (d * d + c * c) / (2.0f * c);
            }
        }
    }
    #pragma unroll
    for (int o = 32; o; o >>= 1) acc += __shfl_down(acc, o);
    __syncthreads();                             // reuse sred
    if ((threadIdx.x & 63) == 0) sred[threadIdx.x >> 6] = acc;
    __syncthreads();
    if (threadIdx.x == 0) {
        acc = (sred[0] + sred[1]) + (sred[2] + sred[3]);
        atomicAdd(out, acc / 4194304.0f);        // exact 2^-22 scale
    }
}

extern "C" void kernel_launch(void* const* d_in, const int* in_sizes, int n_in,
                              void* d_out, int out_size, void* d_ws, size_t ws_size,
                              hipStream_t stream) {
    const float* pred = (const float*)d_in[0];
    const float* gt   = (const float*)d_in[1];
    float* out        = (float*)d_out;
    char* ws          = (char*)d_ws;

    unsigned* maxz    = (unsigned*)(ws + MAXZ_OFF_B);
    unsigned* maxraw  = maxz;                    // [0..95]
    unsigned* maxdiff = maxz + 96;               // [96..98]
    unsigned* done    = maxz + 99;               // [99]
    unsigned* hp      = (unsigned*)(ws + HIST_OFF_B);
    unsigned* bins    = (unsigned*)(ws + BINS_OFF_B);

    bin_kernel<<<4096, 256, 0, stream>>>(pred, gt, bins, maxz, out);
    scan_kernel<<<768, 1024, 0, stream>>>(bins, hp, maxraw);
    tail_kernel<<<768, 256, 0, stream>>>(hp, maxraw, maxdiff, done, out);
}